// Round 1
// baseline (780.670 us; speedup 1.0000x reference)
//
#include <hip/hip_runtime.h>
#include <hip/hip_bf16.h>
#include <math.h>

#define B_  16
#define C_  256
#define N_  256
#define O_  256
#define T_  8192
#define L_  64
#define NC_ (T_ / L_)   // 128 chunks

// ---------------------------------------------------------------------------
// ws layout (floats):
//   Ad     [0, 256)
//   AL     [256, 512)            A_d^64
//   Bd     [512, 512+65536)      B_c * factor
//   p_last [66048, +524288)      per-chunk local end state (k,b,n)
//   carry  [590336, +524288)     state entering each chunk  (k,b,n)
// total ~4.46 MB
// ---------------------------------------------------------------------------

__global__ void k_prep(const float* __restrict__ raw_lambda,
                       const float* __restrict__ B_c,
                       float* __restrict__ Ad, float* __restrict__ AL,
                       float* __restrict__ Bd)
{
    const int n = threadIdx.x;
    const int c = blockIdx.x;
    const float x  = raw_lambda[n];
    const float sp = (x > 20.f) ? x : log1pf(expf(x));   // softplus
    const float lam = -sp;
    const float ad  = expf(lam);                          // DT = 1
    const float factor = (fabsf(lam) > 1e-6f) ? (ad - 1.0f) / lam : 1.0f;
    if (c == 0) {
        Ad[n] = ad;
        float al = ad;
        #pragma unroll
        for (int i = 0; i < 6; ++i) al = al * al;         // ad^64
        AL[n] = al;
    }
    Bd[(size_t)c * N_ + n] = B_c[(size_t)c * N_ + n] * factor;
}

// integer power, e in [0,63]
__device__ inline float ipowf(float a, int e) {
    float p = 1.f, b = a;
    while (e) { if (e & 1) p *= b; b *= b; e >>= 1; }
    return p;
}

// ---------------------------------------------------------------------------
// Phase A: per (chunk k, batch b): GEMM1 for the chunk (x = u^T * Bd), then
// local decay-weighted sum  p_last[k,b,n] = sum_j Ad^(63-j) x_j  (reg reduce).
// ---------------------------------------------------------------------------
__global__ __launch_bounds__(256) void k_phaseA(
    const float* __restrict__ u, const float* __restrict__ Bd,
    const float* __restrict__ Ad, float* __restrict__ p_last)
{
    __shared__ float uT[64][64];     // [c][t]
    __shared__ float bT[64][256];    // [c][n]

    const int k  = blockIdx.x, b = blockIdx.y;
    const int tid = threadIdx.x;
    const int ti = tid & 15;         // t-group: rows ti*4 .. ti*4+3
    const int ni = tid >> 4;         // n-group: cols ni*16 .. ni*16+15
    const int t0 = k * L_;
    const float* ub = u + (size_t)b * C_ * T_ + t0;

    float acc[4][16];
    #pragma unroll
    for (int r = 0; r < 4; ++r)
        #pragma unroll
        for (int j = 0; j < 16; ++j) acc[r][j] = 0.f;

    for (int cc = 0; cc < C_; cc += 64) {
        #pragma unroll
        for (int i = 0; i < 4; ++i) {               // u tile: 64c x 64t
            int idx = tid + i * 256;                // 1024 float4
            int c = idx >> 4, t4 = idx & 15;
            *(float4*)&uT[c][t4 * 4] =
                *(const float4*)(ub + (size_t)(cc + c) * T_ + t4 * 4);
        }
        #pragma unroll
        for (int i = 0; i < 16; ++i) {              // Bd tile: 64c x 256n
            int idx = tid + i * 256;                // 4096 float4
            int c = idx >> 6, n4 = idx & 63;
            *(float4*)&bT[c][n4 * 4] =
                *(const float4*)(Bd + (size_t)(cc + c) * N_ + n4 * 4);
        }
        __syncthreads();
        for (int c = 0; c < 64; ++c) {
            float ur[4], bv[16];
            *(float4*)&ur[0]  = *(const float4*)&uT[c][ti * 4];
            *(float4*)&bv[0]  = *(const float4*)&bT[c][ni * 16 + 0];
            *(float4*)&bv[4]  = *(const float4*)&bT[c][ni * 16 + 4];
            *(float4*)&bv[8]  = *(const float4*)&bT[c][ni * 16 + 8];
            *(float4*)&bv[12] = *(const float4*)&bT[c][ni * 16 + 12];
            #pragma unroll
            for (int r = 0; r < 4; ++r)
                #pragma unroll
                for (int j = 0; j < 16; ++j)
                    acc[r][j] = fmaf(ur[r], bv[j], acc[r][j]);
        }
        __syncthreads();
    }

    // local decay-weighted tail:  sum_r Ad^(63-(4ti+r)) * x[4ti+r][n]
    float part[16];
    #pragma unroll
    for (int j = 0; j < 16; ++j) {
        float a = Ad[ni * 16 + j];
        float h = acc[0][j];
        h = fmaf(h, a, acc[1][j]);
        h = fmaf(h, a, acc[2][j]);
        h = fmaf(h, a, acc[3][j]);                   // a^3 x0 + a^2 x1 + a x2 + x3
        part[j] = h * ipowf(a, 60 - ti * 4);
    }
    // reduce over the 16 ti-lanes (lane-aligned groups of 16 within a wave)
    #pragma unroll
    for (int j = 0; j < 16; ++j) {
        float v = part[j];
        v += __shfl_xor(v, 1);
        v += __shfl_xor(v, 2);
        v += __shfl_xor(v, 4);
        v += __shfl_xor(v, 8);
        part[j] = v;
    }
    if (ti == 0) {
        float* dst = p_last + ((size_t)k * B_ + b) * N_ + ni * 16;
        #pragma unroll
        for (int q = 0; q < 4; ++q)
            *(float4*)(dst + 4 * q) =
                make_float4(part[4*q], part[4*q+1], part[4*q+2], part[4*q+3]);
    }
}

// ---------------------------------------------------------------------------
// Phase B: serial carry scan over the 128 chunks. carry[0]=0,
// carry[k+1] = AL * carry[k] + p_last[k].
// ---------------------------------------------------------------------------
__global__ __launch_bounds__(256) void k_phaseB(
    const float* __restrict__ p_last, const float* __restrict__ AL,
    float* __restrict__ carry)
{
    const int b = blockIdx.x, n = threadIdx.x;
    const float al = AL[n];
    float cur = 0.f;
    #pragma unroll 4
    for (int k = 0; k < NC_; ++k) {
        const size_t idx = ((size_t)k * B_ + b) * N_ + n;
        carry[idx] = cur;
        cur = fmaf(cur, al, p_last[idx]);
    }
}

// ---------------------------------------------------------------------------
// Phase C: per (chunk k, batch b): GEMM1 again -> x tile in LDS, in-place
// scan with carry init -> states, then GEMM2 (states x C) -> y.
// ---------------------------------------------------------------------------
__global__ __launch_bounds__(256) void k_phaseC(
    const float* __restrict__ u, const float* __restrict__ Bd,
    const float* __restrict__ Cm, const float* __restrict__ Ad,
    const float* __restrict__ carry, float* __restrict__ y)
{
    __shared__ float sT[64][257];    // x -> states, [t][n], +1 pad
    __shared__ float uT[64][64];     // [c][t]
    __shared__ float bT[64][256];    // Bd tiles, then C tiles

    const int k  = blockIdx.x, b = blockIdx.y;
    const int tid = threadIdx.x;
    const int ti = tid & 15, ni = tid >> 4;
    const int t0 = k * L_;
    const float* ub = u + (size_t)b * C_ * T_ + t0;

    float acc[4][16];
    #pragma unroll
    for (int r = 0; r < 4; ++r)
        #pragma unroll
        for (int j = 0; j < 16; ++j) acc[r][j] = 0.f;

    // ---- GEMM1: x = u^T * Bd for this chunk ----
    for (int cc = 0; cc < C_; cc += 64) {
        #pragma unroll
        for (int i = 0; i < 4; ++i) {
            int idx = tid + i * 256;
            int c = idx >> 4, t4 = idx & 15;
            *(float4*)&uT[c][t4 * 4] =
                *(const float4*)(ub + (size_t)(cc + c) * T_ + t4 * 4);
        }
        #pragma unroll
        for (int i = 0; i < 16; ++i) {
            int idx = tid + i * 256;
            int c = idx >> 6, n4 = idx & 63;
            *(float4*)&bT[c][n4 * 4] =
                *(const float4*)(Bd + (size_t)(cc + c) * N_ + n4 * 4);
        }
        __syncthreads();
        for (int c = 0; c < 64; ++c) {
            float ur[4], bv[16];
            *(float4*)&ur[0]  = *(const float4*)&uT[c][ti * 4];
            *(float4*)&bv[0]  = *(const float4*)&bT[c][ni * 16 + 0];
            *(float4*)&bv[4]  = *(const float4*)&bT[c][ni * 16 + 4];
            *(float4*)&bv[8]  = *(const float4*)&bT[c][ni * 16 + 8];
            *(float4*)&bv[12] = *(const float4*)&bT[c][ni * 16 + 12];
            #pragma unroll
            for (int r = 0; r < 4; ++r)
                #pragma unroll
                for (int j = 0; j < 16; ++j)
                    acc[r][j] = fmaf(ur[r], bv[j], acc[r][j]);
        }
        __syncthreads();
    }

    // x tile -> LDS
    #pragma unroll
    for (int r = 0; r < 4; ++r)
        #pragma unroll
        for (int j = 0; j < 16; ++j)
            sT[ti * 4 + r][ni * 16 + j] = acc[r][j];
    __syncthreads();

    // ---- scan (thread tid owns state column n = tid) ----
    {
        const int n = tid;
        const float a = Ad[n];
        float s = carry[((size_t)k * B_ + b) * N_ + n];
        #pragma unroll
        for (int j = 0; j < L_; ++j) {
            s = fmaf(s, a, sT[j][n]);
            sT[j][n] = s;
        }
    }
    __syncthreads();

    // ---- GEMM2: y_tile = states(64x256) * C(256x256) ----
    float acc2[4][16];
    #pragma unroll
    for (int r = 0; r < 4; ++r)
        #pragma unroll
        for (int j = 0; j < 16; ++j) acc2[r][j] = 0.f;

    for (int nc = 0; nc < N_; nc += 64) {
        __syncthreads();                 // previous bT readers done
        #pragma unroll
        for (int i = 0; i < 16; ++i) {
            int idx = tid + i * 256;
            int nn = idx >> 6, o4 = idx & 63;
            *(float4*)&bT[nn][o4 * 4] =
                *(const float4*)(Cm + (size_t)(nc + nn) * O_ + o4 * 4);
        }
        __syncthreads();
        for (int nn = 0; nn < 64; ++nn) {
            float s0 = sT[ti * 4 + 0][nc + nn];
            float s1 = sT[ti * 4 + 1][nc + nn];
            float s2 = sT[ti * 4 + 2][nc + nn];
            float s3 = sT[ti * 4 + 3][nc + nn];
            float cv[16];
            *(float4*)&cv[0]  = *(const float4*)&bT[nn][ni * 16 + 0];
            *(float4*)&cv[4]  = *(const float4*)&bT[nn][ni * 16 + 4];
            *(float4*)&cv[8]  = *(const float4*)&bT[nn][ni * 16 + 8];
            *(float4*)&cv[12] = *(const float4*)&bT[nn][ni * 16 + 12];
            #pragma unroll
            for (int j = 0; j < 16; ++j) {
                acc2[0][j] = fmaf(s0, cv[j], acc2[0][j]);
                acc2[1][j] = fmaf(s1, cv[j], acc2[1][j]);
                acc2[2][j] = fmaf(s2, cv[j], acc2[2][j]);
                acc2[3][j] = fmaf(s3, cv[j], acc2[3][j]);
            }
        }
    }

    // ---- write y[b][o][t0 + ti*4 .. +3] ----
    #pragma unroll
    for (int j = 0; j < 16; ++j) {
        const int o = ni * 16 + j;
        float4 v = make_float4(acc2[0][j], acc2[1][j], acc2[2][j], acc2[3][j]);
        *(float4*)(y + ((size_t)b * O_ + o) * T_ + t0 + ti * 4) = v;
    }
}

// ---------------------------------------------------------------------------
extern "C" void kernel_launch(void* const* d_in, const int* in_sizes, int n_in,
                              void* d_out, int out_size, void* d_ws, size_t ws_size,
                              hipStream_t stream)
{
    const float* u  = (const float*)d_in[0];
    const float* rl = (const float*)d_in[1];
    const float* Bc = (const float*)d_in[2];
    const float* Cm = (const float*)d_in[3];
    float* y  = (float*)d_out;
    float* ws = (float*)d_ws;

    float* Ad     = ws;
    float* AL     = ws + 256;
    float* Bd     = ws + 512;
    float* p_last = ws + 512 + (size_t)C_ * N_;
    float* carry  = p_last + (size_t)NC_ * B_ * N_;

    k_prep  <<<dim3(C_),       dim3(N_),  0, stream>>>(rl, Bc, Ad, AL, Bd);
    k_phaseA<<<dim3(NC_, B_),  dim3(256), 0, stream>>>(u, Bd, Ad, p_last);
    k_phaseB<<<dim3(B_),       dim3(N_),  0, stream>>>(p_last, AL, carry);
    k_phaseC<<<dim3(NC_, B_),  dim3(256), 0, stream>>>(u, Bd, Cm, Ad, carry, y);
}

// Round 2
// 138.286 us; speedup vs baseline: 5.6453x; 5.6453x over previous
//
#include <hip/hip_runtime.h>
#include <math.h>

typedef __attribute__((ext_vector_type(8)))  short short8;
typedef __attribute__((ext_vector_type(16))) float f32x16;

#define B_  16
#define C_  256
#define N_  256
#define O_  256
#define T_  8192
#define L_  64
#define NC_ 128

// bf16 helpers (RNE)
__device__ inline unsigned short f2bf(float x) {
    unsigned u = __float_as_uint(x);
    u += 0x7fff + ((u >> 16) & 1);
    return (unsigned short)(u >> 16);
}
__device__ inline float bf2f(unsigned short h) {
    return __uint_as_float(((unsigned)h) << 16);
}

__device__ inline f32x16 zero16() {
    f32x16 z;
    #pragma unroll
    for (int i = 0; i < 16; ++i) z[i] = 0.f;
    return z;
}

// ---------------------------------------------------------------------------
// prep: Ad, AL=Ad^64, and the MFMA b-fragment streams for Bd^T and C^T.
// Fragment-stream layout (per 32-wide K chunk kk, per 32-wide col tile nt,
// per K16 step s): 64 lanes x 8 bf16, lane-linear:
//   idx(c_or_nRow, col) = (((kk*8 + nt)*2 + s)*64 + l)*8 + j
//   with krow&31 = s*16 + hi*8 + j,  l = hi*32 + (col&31),  nt = col>>5.
// b-frag load in kernels = ds_read_b128 at lane-linear offset: conflict-free.
// ---------------------------------------------------------------------------
__global__ __launch_bounds__(256) void k_prep(
    const float* __restrict__ raw_lambda, const float* __restrict__ B_c,
    const float* __restrict__ Cmat,
    float* __restrict__ Ad, float* __restrict__ AL,
    unsigned short* __restrict__ BdKf, unsigned short* __restrict__ CKf)
{
    const int r = blockIdx.x;    // k-dim row (c for Bd, n for C)
    const int t = threadIdx.x;   // col (n for Bd, o for C)
    const int kk = r >> 5, ri = r & 31;
    const int s = ri >> 4, hi = (ri >> 3) & 1, j = ri & 7;
    const int nt = t >> 5, l = (hi << 5) | (t & 31);
    const int idx = (((kk * 8 + nt) * 2 + s) * 64 + l) * 8 + j;

    if (blockIdx.y == 0) {
        const float x  = raw_lambda[t];
        const float sp = (x > 20.f) ? x : log1pf(expf(x));
        const float lam = -sp;
        const float ad  = expf(lam);
        const float factor = (fabsf(lam) > 1e-6f) ? (ad - 1.f) / lam : 1.f;
        if (r == 0) {
            Ad[t] = ad;
            float al = ad;
            #pragma unroll
            for (int i = 0; i < 6; ++i) al *= al;   // ad^64
            AL[t] = al;
        }
        BdKf[idx] = f2bf(B_c[r * N_ + t] * factor);
    } else {
        CKf[idx] = f2bf(Cmat[r * O_ + t]);
    }
}

// ---------------------------------------------------------------------------
// Shared GEMM1: X[64t x 256n] = U_chunk[64t x 256c] * Bd[256c x 256n], MFMA.
// Result written to xs as X[n][t]: [256][66] bf16 (packed pairs, b32 writes).
// Ends with __syncthreads() (X visible to all).
// ---------------------------------------------------------------------------
__device__ __forceinline__ void gemm1_to_X(
    const float* __restrict__ u, const unsigned short* __restrict__ BdKf,
    int b, int k,
    unsigned short* xs,   // [256][66]
    unsigned short* ut,   // [64][40]
    unsigned short* bb)   // [8192]
{
    const int tid = threadIdx.x;
    const int w = tid >> 6, l = tid & 63, lo = l & 31, hi = l >> 5;
    const int t0 = k * L_;

    f32x16 a00 = zero16(), a01 = zero16(), a10 = zero16(), a11 = zero16();

    for (int kk = 0; kk < 8; ++kk) {
        // stage u-chunk transposed -> ut[64t][40c] bf16 (c in [kk*32, +32))
        #pragma unroll
        for (int q = 0; q < 2; ++q) {
            const int i  = q * 256 + tid;
            const int cl = i >> 4, t4 = i & 15;
            const float4 v = *(const float4*)(
                u + ((size_t)b * C_ + kk * 32 + cl) * T_ + t0 + t4 * 4);
            ut[(t4 * 4 + 0) * 40 + cl] = f2bf(v.x);
            ut[(t4 * 4 + 1) * 40 + cl] = f2bf(v.y);
            ut[(t4 * 4 + 2) * 40 + cl] = f2bf(v.z);
            ut[(t4 * 4 + 3) * 40 + cl] = f2bf(v.w);
        }
        // stage Bd fragment chunk (16 KB), lane-linear
        {
            const unsigned short* src = BdKf + kk * 8192;
            #pragma unroll
            for (int q = 0; q < 4; ++q) {
                const int i16 = q * 256 + tid;
                *(int4*)(bb + i16 * 8) = *(const int4*)(src + i16 * 8);
            }
        }
        __syncthreads();
        #pragma unroll
        for (int s = 0; s < 2; ++s) {
            const short8 fa0 = *(const short8*)(ut + (0 * 32 + lo) * 40 + s * 16 + hi * 8);
            const short8 fa1 = *(const short8*)(ut + (1 * 32 + lo) * 40 + s * 16 + hi * 8);
            const short8 fb0 = *(const short8*)(bb + (((2 * w + 0) * 2 + s) * 64 + l) * 8);
            const short8 fb1 = *(const short8*)(bb + (((2 * w + 1) * 2 + s) * 64 + l) * 8);
            a00 = __builtin_amdgcn_mfma_f32_32x32x16_bf16(fa0, fb0, a00, 0, 0, 0);
            a01 = __builtin_amdgcn_mfma_f32_32x32x16_bf16(fa0, fb1, a01, 0, 0, 0);
            a10 = __builtin_amdgcn_mfma_f32_32x32x16_bf16(fa1, fb0, a10, 0, 0, 0);
            a11 = __builtin_amdgcn_mfma_f32_32x32x16_bf16(fa1, fb1, a11, 0, 0, 0);
        }
        __syncthreads();
    }

    // write X[n][t] (bf16 pairs packed into b32): row n, t = 32tt+4hi+8g+2p+e
    #pragma unroll
    for (int tt = 0; tt < 2; ++tt)
        #pragma unroll
        for (int q = 0; q < 2; ++q) {
            const f32x16 a = (tt == 0) ? (q == 0 ? a00 : a01)
                                       : (q == 0 ? a10 : a11);
            const int n = (2 * w + q) * 32 + lo;
            #pragma unroll
            for (int g = 0; g < 4; ++g)
                #pragma unroll
                for (int p = 0; p < 2; ++p) {
                    const unsigned lo16 = f2bf(a[g * 4 + 2 * p + 0]);
                    const unsigned hi16 = f2bf(a[g * 4 + 2 * p + 1]);
                    *(unsigned*)(xs + n * 66 + tt * 32 + hi * 4 + g * 8 + p * 2)
                        = lo16 | (hi16 << 16);
                }
        }
    __syncthreads();
}

// ---------------------------------------------------------------------------
// Phase A: GEMM1 -> X, then p_last[n] = sum_j Ad^(63-j) x_j  (scan from 0).
// ---------------------------------------------------------------------------
__global__ __launch_bounds__(256) void k_phaseA(
    const float* __restrict__ u, const unsigned short* __restrict__ BdKf,
    const float* __restrict__ Ad, float* __restrict__ p_last)
{
    __shared__ __align__(16) unsigned short xs[16896];
    __shared__ __align__(16) unsigned short ut[2560];
    __shared__ __align__(16) unsigned short bb[8192];

    const int k = blockIdx.x, b = blockIdx.y;
    gemm1_to_X(u, BdKf, b, k, xs, ut, bb);

    const int n = threadIdx.x;
    const float a = Ad[n];
    float s = 0.f;
    #pragma unroll
    for (int m = 0; m < 32; ++m) {
        const unsigned dw = *(const unsigned*)(xs + n * 66 + 2 * m);
        s = fmaf(s, a, bf2f((unsigned short)(dw & 0xffff)));
        s = fmaf(s, a, bf2f((unsigned short)(dw >> 16)));
    }
    p_last[((size_t)k * B_ + b) * N_ + n] = s;
}

// ---------------------------------------------------------------------------
// Phase B: carry scan over chunks, LDS-prefetched.
// ---------------------------------------------------------------------------
__global__ __launch_bounds__(256) void k_phaseB(
    const float* __restrict__ p_last, const float* __restrict__ AL,
    float* __restrict__ carry)
{
    __shared__ float buf[32 * 256];
    const int b = blockIdx.x, n = threadIdx.x;
    const float al = AL[n];
    float cur = 0.f;
    for (int kc = 0; kc < 4; ++kc) {
        __syncthreads();
        #pragma unroll
        for (int q = 0; q < 32; ++q)
            buf[q * 256 + n] = p_last[((size_t)(kc * 32 + q) * B_ + b) * N_ + n];
        __syncthreads();
        #pragma unroll
        for (int q = 0; q < 32; ++q) {
            carry[((size_t)(kc * 32 + q) * B_ + b) * N_ + n] = cur;
            cur = fmaf(cur, al, buf[q * 256 + n]);
        }
    }
}

// ---------------------------------------------------------------------------
// Phase C: GEMM1 -> X, scan with carry -> states[t][n] (in-place in xs),
// GEMM2 (states * C) -> y.
// ---------------------------------------------------------------------------
__global__ __launch_bounds__(256) void k_phaseC(
    const float* __restrict__ u, const unsigned short* __restrict__ BdKf,
    const unsigned short* __restrict__ CKf, const float* __restrict__ Ad,
    const float* __restrict__ carry, float* __restrict__ y)
{
    __shared__ __align__(16) unsigned short xs[16896];  // X[256][66] -> states[64][264]
    __shared__ __align__(16) unsigned short ut[2560];
    __shared__ __align__(16) unsigned short bb[8192];

    const int k = blockIdx.x, b = blockIdx.y;
    const int tid = threadIdx.x;
    const int w = tid >> 6, l = tid & 63, lo = l & 31, hi = l >> 5;
    const int t0 = k * L_;

    gemm1_to_X(u, BdKf, b, k, xs, ut, bb);

    // scan: thread owns column n = tid; states kept in registers, then
    // re-written to xs as states[t][n] ([64][264] bf16).
    {
        const int n = tid;
        const float a = Ad[n];
        float s = carry[((size_t)k * B_ + b) * N_ + n];
        float st[64];
        #pragma unroll
        for (int m = 0; m < 32; ++m) {
            const unsigned dw = *(const unsigned*)(xs + n * 66 + 2 * m);
            s = fmaf(s, a, bf2f((unsigned short)(dw & 0xffff)));
            st[2 * m] = s;
            s = fmaf(s, a, bf2f((unsigned short)(dw >> 16)));
            st[2 * m + 1] = s;
        }
        __syncthreads();   // all X reads done before overwrite
        #pragma unroll
        for (int t = 0; t < 64; ++t)
            xs[t * 264 + n] = f2bf(st[t]);
    }
    __syncthreads();

    // GEMM2: y[64t x 256o] = states[64t x 256n] * C[256n x 256o]
    f32x16 c00 = zero16(), c01 = zero16(), c10 = zero16(), c11 = zero16();
    for (int kk = 0; kk < 8; ++kk) {
        __syncthreads();   // previous chunk's frag reads done
        {
            const unsigned short* src = CKf + kk * 8192;
            #pragma unroll
            for (int q = 0; q < 4; ++q) {
                const int i16 = q * 256 + tid;
                *(int4*)(bb + i16 * 8) = *(const int4*)(src + i16 * 8);
            }
        }
        __syncthreads();
        #pragma unroll
        for (int s = 0; s < 2; ++s) {
            const short8 fa0 = *(const short8*)(xs + (0 * 32 + lo) * 264 + kk * 32 + s * 16 + hi * 8);
            const short8 fa1 = *(const short8*)(xs + (1 * 32 + lo) * 264 + kk * 32 + s * 16 + hi * 8);
            const short8 fb0 = *(const short8*)(bb + (((2 * w + 0) * 2 + s) * 64 + l) * 8);
            const short8 fb1 = *(const short8*)(bb + (((2 * w + 1) * 2 + s) * 64 + l) * 8);
            c00 = __builtin_amdgcn_mfma_f32_32x32x16_bf16(fa0, fb0, c00, 0, 0, 0);
            c01 = __builtin_amdgcn_mfma_f32_32x32x16_bf16(fa0, fb1, c01, 0, 0, 0);
            c10 = __builtin_amdgcn_mfma_f32_32x32x16_bf16(fa1, fb0, c10, 0, 0, 0);
            c11 = __builtin_amdgcn_mfma_f32_32x32x16_bf16(fa1, fb1, c11, 0, 0, 0);
        }
    }

    // write y[b][o][t]: per lane o fixed, 4 consecutive t per reg group
    #pragma unroll
    for (int tt = 0; tt < 2; ++tt)
        #pragma unroll
        for (int q = 0; q < 2; ++q) {
            const f32x16 a = (tt == 0) ? (q == 0 ? c00 : c01)
                                       : (q == 0 ? c10 : c11);
            const int o = (2 * w + q) * 32 + lo;
            float* yo = y + ((size_t)b * O_ + o) * T_ + t0 + tt * 32 + hi * 4;
            #pragma unroll
            for (int g = 0; g < 4; ++g) {
                float4 v;
                v.x = a[g * 4 + 0]; v.y = a[g * 4 + 1];
                v.z = a[g * 4 + 2]; v.w = a[g * 4 + 3];
                *(float4*)(yo + g * 8) = v;
            }
        }
}

// ---------------------------------------------------------------------------
extern "C" void kernel_launch(void* const* d_in, const int* in_sizes, int n_in,
                              void* d_out, int out_size, void* d_ws, size_t ws_size,
                              hipStream_t stream)
{
    const float* u  = (const float*)d_in[0];
    const float* rl = (const float*)d_in[1];
    const float* Bc = (const float*)d_in[2];
    const float* Cm = (const float*)d_in[3];
    float* y = (float*)d_out;
    char*  ws = (char*)d_ws;

    float* Ad     = (float*)(ws + 0);
    float* AL     = (float*)(ws + 1024);
    float* p_last = (float*)(ws + 2048);
    float* carry  = (float*)(ws + 2048 + 2097152);
    unsigned short* BdKf = (unsigned short*)(ws + 2048 + 2 * 2097152);
    unsigned short* CKf  = (unsigned short*)(ws + 2048 + 2 * 2097152 + 131072);

    k_prep  <<<dim3(256, 2),  dim3(256), 0, stream>>>(rl, Bc, Cm, Ad, AL, BdKf, CKf);
    k_phaseA<<<dim3(NC_, B_), dim3(256), 0, stream>>>(u, BdKf, Ad, p_last);
    k_phaseB<<<dim3(B_),      dim3(256), 0, stream>>>(p_last, AL, carry);
    k_phaseC<<<dim3(NC_, B_), dim3(256), 0, stream>>>(u, BdKf, CKf, Ad, carry, y);
}

// Round 3
// 125.427 us; speedup vs baseline: 6.2241x; 1.1025x over previous
//
#include <hip/hip_runtime.h>
#include <math.h>

typedef __attribute__((ext_vector_type(8)))  short short8;
typedef __attribute__((ext_vector_type(16))) float f32x16;

#define B_  16
#define C_  256
#define N_  256
#define O_  256
#define T_  8192
#define L_  64
#define NC_ 128
#define XIMG 16896   // shorts per (k,b) X image: [256 n][66 t-packed]

// async global->LDS, 16B per lane; lds base must be wave-uniform (HW adds lane*16)
#define GLL16(gptr, lptr) \
  __builtin_amdgcn_global_load_lds((const __attribute__((address_space(1))) void*)(gptr), \
                                   (__attribute__((address_space(3))) void*)(lptr), 16, 0, 0)

__device__ inline unsigned short f2bf(float x) {
    unsigned u = __float_as_uint(x);
    u += 0x7fff + ((u >> 16) & 1);
    return (unsigned short)(u >> 16);
}
__device__ inline float bf2f(unsigned short h) {
    return __uint_as_float(((unsigned)h) << 16);
}
__device__ inline f32x16 zero16() {
    f32x16 z;
    #pragma unroll
    for (int i = 0; i < 16; ++i) z[i] = 0.f;
    return z;
}

// ---------------------------------------------------------------------------
// prep: Ad, AL=Ad^64, MFMA b-fragment streams for Bd and C (see Round-2 notes).
//   idx = (((kk*8 + nt)*2 + s)*64 + l)*8 + j
// ---------------------------------------------------------------------------
__global__ __launch_bounds__(256) void k_prep(
    const float* __restrict__ raw_lambda, const float* __restrict__ B_c,
    const float* __restrict__ Cmat,
    float* __restrict__ Ad, float* __restrict__ AL,
    unsigned short* __restrict__ BdKf, unsigned short* __restrict__ CKf)
{
    const int r = blockIdx.x;
    const int t = threadIdx.x;
    const int kk = r >> 5, ri = r & 31;
    const int s = ri >> 4, hi = (ri >> 3) & 1, j = ri & 7;
    const int nt = t >> 5, l = (hi << 5) | (t & 31);
    const int idx = (((kk * 8 + nt) * 2 + s) * 64 + l) * 8 + j;

    if (blockIdx.y == 0) {
        const float x  = raw_lambda[t];
        const float sp = (x > 20.f) ? x : log1pf(expf(x));
        const float lam = -sp;
        const float ad  = expf(lam);
        const float factor = (fabsf(lam) > 1e-6f) ? (ad - 1.f) / lam : 1.f;
        if (r == 0) {
            Ad[t] = ad;
            float al = ad;
            #pragma unroll
            for (int i = 0; i < 6; ++i) al *= al;
            AL[t] = al;
        }
        BdKf[idx] = f2bf(B_c[r * N_ + t] * factor);
    } else {
        CKf[idx] = f2bf(Cmat[r * O_ + t]);
    }
}

// ---------------------------------------------------------------------------
// Phase A: pipelined GEMM1 (U_chunk * Bd) -> X image in LDS; p_last scan;
// optional X store to HBM (doX).
// ---------------------------------------------------------------------------
__global__ __launch_bounds__(256) void k_phaseA(
    const float* __restrict__ u, const unsigned short* __restrict__ BdKf,
    const float* __restrict__ Ad, float* __restrict__ p_last,
    unsigned short* __restrict__ X, int doX)
{
    __shared__ __align__(16) unsigned short xs[XIMG];      // 33792 B
    __shared__ __align__(16) unsigned short ut[2][2688];   // [64][42] x2
    __shared__ __align__(16) unsigned short bb[2][8192];   // 16 KB x2

    const int k = blockIdx.x, b = blockIdx.y;
    const int tid = threadIdx.x;
    const int w = tid >> 6, l = tid & 63, lo = l & 31, hi = l >> 5;
    const int t0 = k * L_;
    const float* ub = u + (size_t)b * C_ * T_ + t0;

    auto load_u = [&](float4 v[2], int kk) {
        #pragma unroll
        for (int q = 0; q < 2; ++q) {
            const int i = q * 256 + tid, cl = i >> 4, t4 = i & 15;
            v[q] = *(const float4*)(ub + (size_t)(kk * 32 + cl) * T_ + t4 * 4);
        }
    };
    // pack pairs of c-columns via shfl partner exchange -> b32 LDS writes
    auto cvt_ut = [&](const float4 v[2], unsigned short* utb) {
        unsigned* ud = (unsigned*)utb;
        #pragma unroll
        for (int q = 0; q < 2; ++q) {
            const int i = q * 256 + tid, cl = i >> 4, t4 = i & 15;
            float4 a = v[q], p;
            p.x = __shfl_xor(a.x, 16); p.y = __shfl_xor(a.y, 16);
            p.z = __shfl_xor(a.z, 16); p.w = __shfl_xor(a.w, 16);
            const bool odd = (cl & 1) != 0;
            const float l0 = odd ? p.z : a.x, h0 = odd ? a.z : p.x;
            const float l1 = odd ? p.w : a.y, h1 = odd ? a.w : p.y;
            const int r0 = odd ? 2 : 0;
            ud[(4 * t4 + r0    ) * 21 + (cl >> 1)] = f2bf(l0) | ((unsigned)f2bf(h0) << 16);
            ud[(4 * t4 + r0 + 1) * 21 + (cl >> 1)] = f2bf(l1) | ((unsigned)f2bf(h1) << 16);
        }
    };
    auto stage_bb = [&](int kk, int buf) {
        const char* src = (const char*)(BdKf + kk * 8192);
        #pragma unroll
        for (int q = 0; q < 4; ++q)
            GLL16(src + q * 4096 + w * 1024 + (l << 4),
                  (char*)bb[buf] + q * 4096 + w * 1024);
    };

    f32x16 a00 = zero16(), a01 = zero16(), a10 = zero16(), a11 = zero16();
    float4 va[2], vb[2];

    load_u(va, 0);
    stage_bb(0, 0);
    cvt_ut(va, ut[0]);
    load_u(va, 1);
    __syncthreads();

    #pragma unroll
    for (int kk = 0; kk < 8; ++kk) {
        const int cur = kk & 1;
        if (kk < 7) stage_bb(kk + 1, cur ^ 1);
        if (kk < 6) { if (kk & 1) load_u(va, kk + 2); else load_u(vb, kk + 2); }
        #pragma unroll
        for (int s = 0; s < 2; ++s) {
            const short8 fa0 = *(const short8*)(ut[cur] + (lo     ) * 42 + s * 16 + hi * 8);
            const short8 fa1 = *(const short8*)(ut[cur] + (32 + lo) * 42 + s * 16 + hi * 8);
            const short8 fb0 = *(const short8*)(bb[cur] + (((2 * w + 0) * 2 + s) * 64 + l) * 8);
            const short8 fb1 = *(const short8*)(bb[cur] + (((2 * w + 1) * 2 + s) * 64 + l) * 8);
            a00 = __builtin_amdgcn_mfma_f32_32x32x16_bf16(fa0, fb0, a00, 0, 0, 0);
            a01 = __builtin_amdgcn_mfma_f32_32x32x16_bf16(fa0, fb1, a01, 0, 0, 0);
            a10 = __builtin_amdgcn_mfma_f32_32x32x16_bf16(fa1, fb0, a10, 0, 0, 0);
            a11 = __builtin_amdgcn_mfma_f32_32x32x16_bf16(fa1, fb1, a11, 0, 0, 0);
        }
        if (kk < 7) { if (kk & 1) cvt_ut(vb, ut[cur ^ 1]); else cvt_ut(va, ut[cur ^ 1]); }
        __syncthreads();
    }

    // frags -> xs [256][66] packed bf16 pairs
    #pragma unroll
    for (int tt = 0; tt < 2; ++tt)
        #pragma unroll
        for (int q = 0; q < 2; ++q) {
            const f32x16 a = (tt == 0) ? (q == 0 ? a00 : a01) : (q == 0 ? a10 : a11);
            const int n = (2 * w + q) * 32 + lo;
            #pragma unroll
            for (int g = 0; g < 4; ++g)
                #pragma unroll
                for (int p = 0; p < 2; ++p)
                    *(unsigned*)(xs + n * 66 + tt * 32 + hi * 4 + g * 8 + p * 2)
                        = f2bf(a[g * 4 + 2 * p]) | ((unsigned)f2bf(a[g * 4 + 2 * p + 1]) << 16);
        }
    __syncthreads();

    // p_last scan
    {
        const float ad = Ad[tid];
        float s = 0.f;
        const unsigned* row = (const unsigned*)xs + tid * 33;
        #pragma unroll
        for (int m = 0; m < 32; ++m) {
            const unsigned dw = row[m];
            s = fmaf(s, ad, bf2f((unsigned short)(dw & 0xffff)));
            s = fmaf(s, ad, bf2f((unsigned short)(dw >> 16)));
        }
        p_last[((size_t)k * B_ + b) * N_ + tid] = s;
    }

    // X image -> HBM (linear, coalesced)
    if (doX) {
        const int4* src = (const int4*)xs;
        int4* dst = (int4*)(X + ((size_t)k * B_ + b) * XIMG);
        #pragma unroll
        for (int q = 0; q < 8; ++q) dst[q * 256 + tid] = src[q * 256 + tid];
        if (tid < 64) dst[2048 + tid] = src[2048 + tid];
    }
}

// ---------------------------------------------------------------------------
// Phase B: carry scan over chunks, LDS-prefetched.
// ---------------------------------------------------------------------------
__global__ __launch_bounds__(256) void k_phaseB(
    const float* __restrict__ p_last, const float* __restrict__ AL,
    float* __restrict__ carry)
{
    __shared__ float buf[32 * 256];
    const int b = blockIdx.x, n = threadIdx.x;
    const float al = AL[n];
    float cur = 0.f;
    for (int kc = 0; kc < 4; ++kc) {
        __syncthreads();
        #pragma unroll
        for (int q = 0; q < 32; ++q)
            buf[q * 256 + n] = p_last[((size_t)(kc * 32 + q) * B_ + b) * N_ + n];
        __syncthreads();
        #pragma unroll
        for (int q = 0; q < 32; ++q) {
            carry[((size_t)(kc * 32 + q) * B_ + b) * N_ + n] = cur;
            cur = fmaf(cur, al, buf[q * 256 + n]);
        }
    }
}

// ---------------------------------------------------------------------------
// Phase C (X path): load X image, scan with carry, states -> swizzled LDS,
// pipelined GEMM2 -> y.
// ---------------------------------------------------------------------------
__global__ __launch_bounds__(256) void k_phaseC(
    const unsigned short* __restrict__ X, const unsigned short* __restrict__ CKf,
    const float* __restrict__ Ad, const float* __restrict__ carry,
    float* __restrict__ y)
{
    __shared__ __align__(16) unsigned short xs[XIMG];      // X image -> states [64][264]
    __shared__ __align__(16) unsigned short bb[2][8192];

    const int k = blockIdx.x, b = blockIdx.y;
    const int tid = threadIdx.x;
    const int w = tid >> 6, l = tid & 63, lo = l & 31, hi = l >> 5;
    const int t0 = k * L_;

    auto stage_bb = [&](int kk, int buf) {
        const char* src = (const char*)(CKf + kk * 8192);
        #pragma unroll
        for (int q = 0; q < 4; ++q)
            GLL16(src + q * 4096 + w * 1024 + (l << 4),
                  (char*)bb[buf] + q * 4096 + w * 1024);
    };

    stage_bb(0, 0);
    const float cv = carry[((size_t)k * B_ + b) * N_ + tid];
    {
        const char* src = (const char*)(X + ((size_t)k * B_ + b) * XIMG);
        #pragma unroll
        for (int q = 0; q < 8; ++q)
            GLL16(src + q * 4096 + w * 1024 + (l << 4),
                  (char*)xs + q * 4096 + w * 1024);
        if (w == 0) GLL16(src + 32768 + (l << 4), (char*)xs + 32768);
    }
    __syncthreads();

    // scan (thread owns n = tid)
    float st[64];
    {
        const float ad = Ad[tid];
        float s = cv;
        const unsigned* row = (const unsigned*)xs + tid * 33;
        #pragma unroll
        for (int m = 0; m < 32; ++m) {
            const unsigned dw = row[m];
            s = fmaf(s, ad, bf2f((unsigned short)(dw & 0xffff)));  st[2 * m]     = s;
            s = fmaf(s, ad, bf2f((unsigned short)(dw >> 16)));     st[2 * m + 1] = s;
        }
    }
    __syncthreads();
    // states write [64][264], col-block XOR swizzle keyed on (t>>3)&3
    {
        const int nb = tid >> 3, nl = tid & 7;
        #pragma unroll
        for (int t = 0; t < 64; ++t)
            xs[t * 264 + (((nb ^ ((t >> 3) & 3)) << 3) | nl)] = f2bf(st[t]);
    }
    __syncthreads();

    f32x16 c00 = zero16(), c01 = zero16(), c10 = zero16(), c11 = zero16();
    #pragma unroll
    for (int kk = 0; kk < 8; ++kk) {
        const int cur = kk & 1;
        if (kk < 7) stage_bb(kk + 1, cur ^ 1);
        #pragma unroll
        for (int s = 0; s < 2; ++s) {
            short8 fa[2];
            #pragma unroll
            for (int tt = 0; tt < 2; ++tt) {
                const int t = tt * 32 + lo;
                const int blk = (kk * 4 + s * 2 + hi) ^ ((t >> 3) & 3);
                fa[tt] = *(const short8*)(xs + t * 264 + blk * 8);
            }
            const short8 fb0 = *(const short8*)(bb[cur] + (((2 * w + 0) * 2 + s) * 64 + l) * 8);
            const short8 fb1 = *(const short8*)(bb[cur] + (((2 * w + 1) * 2 + s) * 64 + l) * 8);
            c00 = __builtin_amdgcn_mfma_f32_32x32x16_bf16(fa[0], fb0, c00, 0, 0, 0);
            c01 = __builtin_amdgcn_mfma_f32_32x32x16_bf16(fa[0], fb1, c01, 0, 0, 0);
            c10 = __builtin_amdgcn_mfma_f32_32x32x16_bf16(fa[1], fb0, c10, 0, 0, 0);
            c11 = __builtin_amdgcn_mfma_f32_32x32x16_bf16(fa[1], fb1, c11, 0, 0, 0);
        }
        __syncthreads();
    }

    #pragma unroll
    for (int tt = 0; tt < 2; ++tt)
        #pragma unroll
        for (int q = 0; q < 2; ++q) {
            const f32x16 a = (tt == 0) ? (q == 0 ? c00 : c01) : (q == 0 ? c10 : c11);
            const int o = (2 * w + q) * 32 + lo;
            float* yo = y + ((size_t)b * O_ + o) * T_ + t0 + tt * 32 + hi * 4;
            #pragma unroll
            for (int g = 0; g < 4; ++g) {
                float4 v;
                v.x = a[g * 4 + 0]; v.y = a[g * 4 + 1];
                v.z = a[g * 4 + 2]; v.w = a[g * 4 + 3];
                *(float4*)(yo + g * 8) = v;
            }
        }
}

// ---------------------------------------------------------------------------
// Fallback Phase C (recompute GEMM1; Round-2 proven) — used if ws too small.
// ---------------------------------------------------------------------------
__device__ __forceinline__ void gemm1_rc(
    const float* __restrict__ u, const unsigned short* __restrict__ BdKf,
    int b, int k, unsigned short* xs, unsigned short* ut, unsigned short* bb)
{
    const int tid = threadIdx.x;
    const int w = tid >> 6, l = tid & 63, lo = l & 31, hi = l >> 5;
    const int t0 = k * L_;
    f32x16 a00 = zero16(), a01 = zero16(), a10 = zero16(), a11 = zero16();
    for (int kk = 0; kk < 8; ++kk) {
        #pragma unroll
        for (int q = 0; q < 2; ++q) {
            const int i = q * 256 + tid, cl = i >> 4, t4 = i & 15;
            const float4 v = *(const float4*)(
                u + ((size_t)b * C_ + kk * 32 + cl) * T_ + t0 + t4 * 4);
            ut[(t4 * 4 + 0) * 40 + cl] = f2bf(v.x);
            ut[(t4 * 4 + 1) * 40 + cl] = f2bf(v.y);
            ut[(t4 * 4 + 2) * 40 + cl] = f2bf(v.z);
            ut[(t4 * 4 + 3) * 40 + cl] = f2bf(v.w);
        }
        {
            const unsigned short* src = BdKf + kk * 8192;
            #pragma unroll
            for (int q = 0; q < 4; ++q) {
                const int i16 = q * 256 + tid;
                *(int4*)(bb + i16 * 8) = *(const int4*)(src + i16 * 8);
            }
        }
        __syncthreads();
        #pragma unroll
        for (int s = 0; s < 2; ++s) {
            const short8 fa0 = *(const short8*)(ut + (0 * 32 + lo) * 40 + s * 16 + hi * 8);
            const short8 fa1 = *(const short8*)(ut + (1 * 32 + lo) * 40 + s * 16 + hi * 8);
            const short8 fb0 = *(const short8*)(bb + (((2 * w + 0) * 2 + s) * 64 + l) * 8);
            const short8 fb1 = *(const short8*)(bb + (((2 * w + 1) * 2 + s) * 64 + l) * 8);
            a00 = __builtin_amdgcn_mfma_f32_32x32x16_bf16(fa0, fb0, a00, 0, 0, 0);
            a01 = __builtin_amdgcn_mfma_f32_32x32x16_bf16(fa0, fb1, a01, 0, 0, 0);
            a10 = __builtin_amdgcn_mfma_f32_32x32x16_bf16(fa1, fb0, a10, 0, 0, 0);
            a11 = __builtin_amdgcn_mfma_f32_32x32x16_bf16(fa1, fb1, a11, 0, 0, 0);
        }
        __syncthreads();
    }
    #pragma unroll
    for (int tt = 0; tt < 2; ++tt)
        #pragma unroll
        for (int q = 0; q < 2; ++q) {
            const f32x16 a = (tt == 0) ? (q == 0 ? a00 : a01) : (q == 0 ? a10 : a11);
            const int n = (2 * w + q) * 32 + lo;
            #pragma unroll
            for (int g = 0; g < 4; ++g)
                #pragma unroll
                for (int p = 0; p < 2; ++p)
                    *(unsigned*)(xs + n * 66 + tt * 32 + hi * 4 + g * 8 + p * 2)
                        = f2bf(a[g * 4 + 2 * p]) | ((unsigned)f2bf(a[g * 4 + 2 * p + 1]) << 16);
        }
    __syncthreads();
}

__global__ __launch_bounds__(256) void k_phaseC_rc(
    const float* __restrict__ u, const unsigned short* __restrict__ BdKf,
    const unsigned short* __restrict__ CKf, const float* __restrict__ Ad,
    const float* __restrict__ carry, float* __restrict__ y)
{
    __shared__ __align__(16) unsigned short xs[XIMG];
    __shared__ __align__(16) unsigned short ut[2560];
    __shared__ __align__(16) unsigned short bb[8192];

    const int k = blockIdx.x, b = blockIdx.y;
    const int tid = threadIdx.x;
    const int w = tid >> 6, l = tid & 63, lo = l & 31, hi = l >> 5;
    const int t0 = k * L_;

    gemm1_rc(u, BdKf, b, k, xs, ut, bb);

    {
        const float a = Ad[tid];
        float s = carry[((size_t)k * B_ + b) * N_ + tid];
        float st[64];
        #pragma unroll
        for (int m = 0; m < 32; ++m) {
            const unsigned dw = *(const unsigned*)(xs + tid * 66 + 2 * m);
            s = fmaf(s, a, bf2f((unsigned short)(dw & 0xffff)));  st[2 * m] = s;
            s = fmaf(s, a, bf2f((unsigned short)(dw >> 16)));     st[2 * m + 1] = s;
        }
        __syncthreads();
        #pragma unroll
        for (int t = 0; t < 64; ++t) xs[t * 264 + tid] = f2bf(st[t]);
    }
    __syncthreads();

    f32x16 c00 = zero16(), c01 = zero16(), c10 = zero16(), c11 = zero16();
    for (int kk = 0; kk < 8; ++kk) {
        __syncthreads();
        {
            const unsigned short* src = CKf + kk * 8192;
            #pragma unroll
            for (int q = 0; q < 4; ++q) {
                const int i16 = q * 256 + tid;
                *(int4*)(bb + i16 * 8) = *(const int4*)(src + i16 * 8);
            }
        }
        __syncthreads();
        #pragma unroll
        for (int s = 0; s < 2; ++s) {
            const short8 fa0 = *(const short8*)(xs + (0 * 32 + lo) * 264 + kk * 32 + s * 16 + hi * 8);
            const short8 fa1 = *(const short8*)(xs + (1 * 32 + lo) * 264 + kk * 32 + s * 16 + hi * 8);
            const short8 fb0 = *(const short8*)(bb + (((2 * w + 0) * 2 + s) * 64 + l) * 8);
            const short8 fb1 = *(const short8*)(bb + (((2 * w + 1) * 2 + s) * 64 + l) * 8);
            c00 = __builtin_amdgcn_mfma_f32_32x32x16_bf16(fa0, fb0, c00, 0, 0, 0);
            c01 = __builtin_amdgcn_mfma_f32_32x32x16_bf16(fa0, fb1, c01, 0, 0, 0);
            c10 = __builtin_amdgcn_mfma_f32_32x32x16_bf16(fa1, fb0, c10, 0, 0, 0);
            c11 = __builtin_amdgcn_mfma_f32_32x32x16_bf16(fa1, fb1, c11, 0, 0, 0);
        }
    }

    #pragma unroll
    for (int tt = 0; tt < 2; ++tt)
        #pragma unroll
        for (int q = 0; q < 2; ++q) {
            const f32x16 a = (tt == 0) ? (q == 0 ? c00 : c01) : (q == 0 ? c10 : c11);
            const int o = (2 * w + q) * 32 + lo;
            float* yo = y + ((size_t)b * O_ + o) * T_ + t0 + tt * 32 + hi * 4;
            #pragma unroll
            for (int g = 0; g < 4; ++g) {
                float4 v;
                v.x = a[g * 4 + 0]; v.y = a[g * 4 + 1];
                v.z = a[g * 4 + 2]; v.w = a[g * 4 + 3];
                *(float4*)(yo + g * 8) = v;
            }
        }
}

// ---------------------------------------------------------------------------
extern "C" void kernel_launch(void* const* d_in, const int* in_sizes, int n_in,
                              void* d_out, int out_size, void* d_ws, size_t ws_size,
                              hipStream_t stream)
{
    const float* u  = (const float*)d_in[0];
    const float* rl = (const float*)d_in[1];
    const float* Bc = (const float*)d_in[2];
    const float* Cm = (const float*)d_in[3];
    float* y  = (float*)d_out;
    char*  ws = (char*)d_ws;

    float* Ad     = (float*)(ws + 0);
    float* AL     = (float*)(ws + 1024);
    float* p_last = (float*)(ws + 2048);
    float* carry  = (float*)(ws + 2048 + 2097152);
    unsigned short* BdKf = (unsigned short*)(ws + 2048 + 2 * 2097152);
    unsigned short* CKf  = (unsigned short*)(ws + 2048 + 2 * 2097152 + 131072);
    unsigned short* X    = (unsigned short*)(ws + 2048 + 2 * 2097152 + 2 * 131072);
    const size_t need = 2048 + 2ull * 2097152 + 2ull * 131072
                      + (size_t)NC_ * B_ * XIMG * 2;
    const int doX = (ws_size >= need) ? 1 : 0;

    k_prep  <<<dim3(256, 2),  dim3(256), 0, stream>>>(rl, Bc, Cm, Ad, AL, BdKf, CKf);
    k_phaseA<<<dim3(NC_, B_), dim3(256), 0, stream>>>(u, BdKf, Ad, p_last, X, doX);
    k_phaseB<<<dim3(B_),      dim3(256), 0, stream>>>(p_last, AL, carry);
    if (doX)
        k_phaseC<<<dim3(NC_, B_), dim3(256), 0, stream>>>(X, CKf, Ad, carry, y);
    else
        k_phaseC_rc<<<dim3(NC_, B_), dim3(256), 0, stream>>>(u, BdKf, CKf, Ad, carry, y);
}

// Round 4
// 120.032 us; speedup vs baseline: 6.5039x; 1.0449x over previous
//
#include <hip/hip_runtime.h>
#include <math.h>

typedef __attribute__((ext_vector_type(8)))  short short8;
typedef __attribute__((ext_vector_type(16))) float f32x16;

#define B_  16
#define C_  256
#define N_  256
#define O_  256
#define T_  8192
#define L_  64
#define NC_ 128

// async global->LDS, 16B per lane; lds base wave-uniform (HW adds lane*16)
#define GLL16(gptr, lptr) \
  __builtin_amdgcn_global_load_lds((const __attribute__((address_space(1))) void*)(gptr), \
                                   (__attribute__((address_space(3))) void*)(lptr), 16, 0, 0)

__device__ inline unsigned short f2bf(float x) {
    unsigned u = __float_as_uint(x);
    u += 0x7fff + ((u >> 16) & 1);
    return (unsigned short)(u >> 16);
}
__device__ inline float bf2f(unsigned short h) {
    return __uint_as_float(((unsigned)h) << 16);
}
__device__ inline f32x16 zero16() {
    f32x16 z;
    #pragma unroll
    for (int i = 0; i < 16; ++i) z[i] = 0.f;
    return z;
}

// ---------------------------------------------------------------------------
// prep: Ad, AL=Ad^64, MFMA b-fragment streams for Bd and C.
//   idx = (((kk*8 + nt)*2 + s)*64 + l)*8 + j
// ---------------------------------------------------------------------------
__global__ __launch_bounds__(256) void k_prep(
    const float* __restrict__ raw_lambda, const float* __restrict__ B_c,
    const float* __restrict__ Cmat,
    float* __restrict__ Ad, float* __restrict__ AL,
    unsigned short* __restrict__ BdKf, unsigned short* __restrict__ CKf)
{
    const int r = blockIdx.x;
    const int t = threadIdx.x;
    const int kk = r >> 5, ri = r & 31;
    const int s = ri >> 4, hi = (ri >> 3) & 1, j = ri & 7;
    const int nt = t >> 5, l = (hi << 5) | (t & 31);
    const int idx = (((kk * 8 + nt) * 2 + s) * 64 + l) * 8 + j;

    if (blockIdx.y == 0) {
        const float x  = raw_lambda[t];
        const float sp = (x > 20.f) ? x : log1pf(expf(x));
        const float lam = -sp;
        const float ad  = expf(lam);
        const float factor = (fabsf(lam) > 1e-6f) ? (ad - 1.f) / lam : 1.f;
        if (r == 0) {
            Ad[t] = ad;
            float al = ad;
            #pragma unroll
            for (int i = 0; i < 6; ++i) al *= al;
            AL[t] = al;
        }
        BdKf[idx] = f2bf(B_c[r * N_ + t] * factor);
    } else {
        CKf[idx] = f2bf(Cmat[r * O_ + t]);
    }
}

// ---------------------------------------------------------------------------
// Phase A: pipelined GEMM1 (U_chunk * Bd); X stored to HBM directly from
// frags (packed bf16, frag layout); p_last computed in-register.
// X dword layout per (k,b) block (8192 dw):  w*2048 + f*512 + h*256 + l*4 + c
//   f = tt*2+q (frag a_{tt,q}), h = dword half (regs 0-7 / 8-15), l = lane.
// ---------------------------------------------------------------------------
__global__ __launch_bounds__(256) void k_phaseA(
    const float* __restrict__ u, const unsigned short* __restrict__ BdKf,
    const float* __restrict__ Ad, float* __restrict__ p_last,
    unsigned short* __restrict__ X, int doX)
{
    __shared__ __align__(16) unsigned short ut[2][2688];   // [64][42] x2
    __shared__ __align__(16) unsigned short bb[2][8192];   // 16 KB x2

    const int k = blockIdx.x, b = blockIdx.y;
    const int tid = threadIdx.x;
    const int w = tid >> 6, l = tid & 63, lo = l & 31, hi = l >> 5;
    const int t0 = k * L_;
    const float* ub = u + (size_t)b * C_ * T_ + t0;

    // Ad for this lane's two column groups (hoisted loads)
    const float adq0 = Ad[(2 * w + 0) * 32 + lo];
    const float adq1 = Ad[(2 * w + 1) * 32 + lo];

    auto load_u = [&](float4 v[2], int kk) {
        #pragma unroll
        for (int q = 0; q < 2; ++q) {
            const int i = q * 256 + tid, cl = i >> 4, t4 = i & 15;
            v[q] = *(const float4*)(ub + (size_t)(kk * 32 + cl) * T_ + t4 * 4);
        }
    };
    auto cvt_ut = [&](const float4 v[2], unsigned short* utb) {
        unsigned* ud = (unsigned*)utb;
        #pragma unroll
        for (int q = 0; q < 2; ++q) {
            const int i = q * 256 + tid, cl = i >> 4, t4 = i & 15;
            float4 a = v[q], p;
            p.x = __shfl_xor(a.x, 16); p.y = __shfl_xor(a.y, 16);
            p.z = __shfl_xor(a.z, 16); p.w = __shfl_xor(a.w, 16);
            const bool odd = (cl & 1) != 0;
            const float l0 = odd ? p.z : a.x, h0 = odd ? a.z : p.x;
            const float l1 = odd ? p.w : a.y, h1 = odd ? a.w : p.y;
            const int r0 = odd ? 2 : 0;
            ud[(4 * t4 + r0    ) * 21 + (cl >> 1)] = f2bf(l0) | ((unsigned)f2bf(h0) << 16);
            ud[(4 * t4 + r0 + 1) * 21 + (cl >> 1)] = f2bf(l1) | ((unsigned)f2bf(h1) << 16);
        }
    };
    auto stage_bb = [&](int kk, int buf) {
        const char* src = (const char*)(BdKf + kk * 8192);
        #pragma unroll
        for (int q = 0; q < 4; ++q)
            GLL16(src + q * 4096 + w * 1024 + (l << 4),
                  (char*)bb[buf] + q * 4096 + w * 1024);
    };

    f32x16 a00 = zero16(), a01 = zero16(), a10 = zero16(), a11 = zero16();
    float4 va[2], vb[2];

    load_u(va, 0);
    stage_bb(0, 0);
    cvt_ut(va, ut[0]);
    load_u(va, 1);
    __syncthreads();

    #pragma unroll
    for (int kk = 0; kk < 8; ++kk) {
        const int cur = kk & 1;
        if (kk < 7) stage_bb(kk + 1, cur ^ 1);
        if (kk < 6) { if (kk & 1) load_u(va, kk + 2); else load_u(vb, kk + 2); }
        #pragma unroll
        for (int s = 0; s < 2; ++s) {
            const short8 fa0 = *(const short8*)(ut[cur] + (lo     ) * 42 + s * 16 + hi * 8);
            const short8 fa1 = *(const short8*)(ut[cur] + (32 + lo) * 42 + s * 16 + hi * 8);
            const short8 fb0 = *(const short8*)(bb[cur] + (((2 * w + 0) * 2 + s) * 64 + l) * 8);
            const short8 fb1 = *(const short8*)(bb[cur] + (((2 * w + 1) * 2 + s) * 64 + l) * 8);
            a00 = __builtin_amdgcn_mfma_f32_32x32x16_bf16(fa0, fb0, a00, 0, 0, 0);
            a01 = __builtin_amdgcn_mfma_f32_32x32x16_bf16(fa0, fb1, a01, 0, 0, 0);
            a10 = __builtin_amdgcn_mfma_f32_32x32x16_bf16(fa1, fb0, a10, 0, 0, 0);
            a11 = __builtin_amdgcn_mfma_f32_32x32x16_bf16(fa1, fb1, a11, 0, 0, 0);
        }
        if (kk < 7) { if (kk & 1) cvt_ut(vb, ut[cur ^ 1]); else cvt_ut(va, ut[cur ^ 1]); }
        __syncthreads();
    }

    // ---- X store: packed bf16, frag layout, fully coalesced dwordx4 ----
    if (doX) {
        unsigned* Xd = (unsigned*)X + (size_t)(k * B_ + b) * 8192;
        #pragma unroll
        for (int f = 0; f < 4; ++f) {
            const f32x16 a = (f == 0) ? a00 : (f == 1) ? a01 : (f == 2) ? a10 : a11;
            unsigned dw[8];
            #pragma unroll
            for (int d = 0; d < 8; ++d)
                dw[d] = f2bf(a[2 * d]) | ((unsigned)f2bf(a[2 * d + 1]) << 16);
            unsigned* base = Xd + w * 2048 + f * 512 + l * 4;
            *(int4*)(base)       = *(const int4*)&dw[0];
            *(int4*)(base + 256) = *(const int4*)&dw[4];
        }
    }

    // ---- p_last in-register: sum_t Ad^(63-t) x[t][n] from frags ----
    // row map: t = tt*32 + (reg&3) + 8*(reg>>2) + 4*hi
    {
        float p[2];
        #pragma unroll
        for (int q = 0; q < 2; ++q) {
            const float ad = q ? adq1 : adq0;
            const float ad2 = ad * ad, ad4 = ad2 * ad2, ad8 = ad4 * ad4;
            const float ad16 = ad8 * ad8, ad32 = ad16 * ad16;
            float full[2];
            #pragma unroll
            for (int tt = 0; tt < 2; ++tt) {
                const f32x16 a = (tt == 0) ? (q == 0 ? a00 : a01)
                                           : (q == 0 ? a10 : a11);
                float v[4];
                #pragma unroll
                for (int g = 0; g < 4; ++g)
                    v[g] = fmaf(fmaf(fmaf(a[4*g], ad, a[4*g+1]), ad, a[4*g+2]), ad, a[4*g+3]);
                const float H = fmaf(fmaf(fmaf(v[0], ad8, v[1]), ad8, v[2]), ad8, v[3]);
                float P = hi ? H : H * ad4;      // * Ad^(4-4hi)
                P += __shfl_xor(P, 32);
                full[tt] = P;
            }
            p[q] = fmaf(full[0], ad32, full[1]);
        }
        if (hi == 0) {
            float* dst = p_last + (size_t)(k * B_ + b) * N_;
            dst[(2 * w + 0) * 32 + lo] = p[0];
            dst[(2 * w + 1) * 32 + lo] = p[1];
        }
    }
}

// ---------------------------------------------------------------------------
// Phase B: carry scan over chunks, LDS-prefetched.
// ---------------------------------------------------------------------------
__global__ __launch_bounds__(256) void k_phaseB(
    const float* __restrict__ p_last, const float* __restrict__ AL,
    float* __restrict__ carry)
{
    __shared__ float buf[32 * 256];
    const int b = blockIdx.x, n = threadIdx.x;
    const float al = AL[n];
    float cur = 0.f;
    for (int kc = 0; kc < 4; ++kc) {
        __syncthreads();
        #pragma unroll
        for (int q = 0; q < 32; ++q)
            buf[q * 256 + n] = p_last[((size_t)(kc * 32 + q) * B_ + b) * N_ + n];
        __syncthreads();
        #pragma unroll
        for (int q = 0; q < 32; ++q) {
            carry[((size_t)(kc * 32 + q) * B_ + b) * N_ + n] = cur;
            cur = fmaf(cur, al, buf[q * 256 + n]);
        }
    }
}

// ---------------------------------------------------------------------------
// Phase C (X path): GLL16 frag-layout X -> LDS; per-thread column gather
// (8 ds_read_b128) -> scan -> states (swizzled, reusing X region) -> GEMM2.
// ---------------------------------------------------------------------------
__global__ __launch_bounds__(256) void k_phaseC(
    const unsigned short* __restrict__ X, const unsigned short* __restrict__ CKf,
    const float* __restrict__ Ad, const float* __restrict__ carry,
    float* __restrict__ y)
{
    __shared__ __align__(16) unsigned short xs[16896];  // X (32 KB) -> states [64][264]
    __shared__ __align__(16) unsigned short bb[2][8192];

    const int k = blockIdx.x, b = blockIdx.y;
    const int tid = threadIdx.x;
    const int w = tid >> 6, l = tid & 63, lo = l & 31, hi = l >> 5;
    const int t0 = k * L_;

    auto stage_bb = [&](int kk, int buf) {
        const char* src = (const char*)(CKf + kk * 8192);
        #pragma unroll
        for (int q = 0; q < 4; ++q)
            GLL16(src + q * 4096 + w * 1024 + (l << 4),
                  (char*)bb[buf] + q * 4096 + w * 1024);
    };

    stage_bb(0, 0);
    {
        const char* src = (const char*)X + (size_t)(k * B_ + b) * 32768;
        #pragma unroll
        for (int q = 0; q < 8; ++q)
            GLL16(src + q * 4096 + w * 1024 + (l << 4),
                  (char*)xs + q * 4096 + w * 1024);
    }
    const float cv = carry[(size_t)(k * B_ + b) * N_ + tid];
    const float ad = Ad[tid];
    __syncthreads();

    // gather this thread's column (n = tid) from frag-layout X
    unsigned arr[2][2][8];   // [tt][hi][dw]
    {
        const unsigned* xd = (const unsigned*)xs;
        const int w2 = tid >> 6, q2 = (tid >> 5) & 1, lo2 = tid & 31;
        #pragma unroll
        for (int tt = 0; tt < 2; ++tt)
            #pragma unroll
            for (int h2 = 0; h2 < 2; ++h2) {
                const unsigned* p = xd + w2 * 2048 + (tt * 2 + q2) * 512
                                       + (h2 * 32 + lo2) * 4;
                *(int4*)&arr[tt][h2][0] = *(const int4*)(p);
                *(int4*)&arr[tt][h2][4] = *(const int4*)(p + 256);
            }
    }
    __syncthreads();   // all X reads done before states overwrite

    // scan + write states [64][264] with col-block XOR swizzle
    {
        const int nb = tid >> 3, nl = tid & 7;
        float s = cv;
        #pragma unroll
        for (int tt = 0; tt < 2; ++tt)
            #pragma unroll
            for (int g = 0; g < 4; ++g)
                #pragma unroll
                for (int h2 = 0; h2 < 2; ++h2) {
                    const unsigned d0 = arr[tt][h2][2 * g];
                    const unsigned d1 = arr[tt][h2][2 * g + 1];
                    const int tb = tt * 32 + 8 * g + 4 * h2;
                    const int swz = (((nb ^ ((tb >> 3) & 3)) << 3) | nl);
                    s = fmaf(s, ad, bf2f((unsigned short)(d0 & 0xffff)));
                    xs[(tb + 0) * 264 + swz] = f2bf(s);
                    s = fmaf(s, ad, bf2f((unsigned short)(d0 >> 16)));
                    xs[(tb + 1) * 264 + swz] = f2bf(s);
                    s = fmaf(s, ad, bf2f((unsigned short)(d1 & 0xffff)));
                    xs[(tb + 2) * 264 + swz] = f2bf(s);
                    s = fmaf(s, ad, bf2f((unsigned short)(d1 >> 16)));
                    xs[(tb + 3) * 264 + swz] = f2bf(s);
                }
    }
    __syncthreads();

    // GEMM2: y[64t x 256o] = states * C, pipelined
    f32x16 c00 = zero16(), c01 = zero16(), c10 = zero16(), c11 = zero16();
    #pragma unroll
    for (int kk = 0; kk < 8; ++kk) {
        const int cur = kk & 1;
        if (kk < 7) stage_bb(kk + 1, cur ^ 1);
        #pragma unroll
        for (int s = 0; s < 2; ++s) {
            short8 fa[2];
            #pragma unroll
            for (int tt = 0; tt < 2; ++tt) {
                const int t = tt * 32 + lo;
                const int blk = (kk * 4 + s * 2 + hi) ^ ((t >> 3) & 3);
                fa[tt] = *(const short8*)(xs + t * 264 + blk * 8);
            }
            const short8 fb0 = *(const short8*)(bb[cur] + (((2 * w + 0) * 2 + s) * 64 + l) * 8);
            const short8 fb1 = *(const short8*)(bb[cur] + (((2 * w + 1) * 2 + s) * 64 + l) * 8);
            c00 = __builtin_amdgcn_mfma_f32_32x32x16_bf16(fa[0], fb0, c00, 0, 0, 0);
            c01 = __builtin_amdgcn_mfma_f32_32x32x16_bf16(fa[0], fb1, c01, 0, 0, 0);
            c10 = __builtin_amdgcn_mfma_f32_32x32x16_bf16(fa[1], fb0, c10, 0, 0, 0);
            c11 = __builtin_amdgcn_mfma_f32_32x32x16_bf16(fa[1], fb1, c11, 0, 0, 0);
        }
        __syncthreads();
    }

    #pragma unroll
    for (int tt = 0; tt < 2; ++tt)
        #pragma unroll
        for (int q = 0; q < 2; ++q) {
            const f32x16 a = (tt == 0) ? (q == 0 ? c00 : c01) : (q == 0 ? c10 : c11);
            const int o = (2 * w + q) * 32 + lo;
            float* yo = y + ((size_t)b * O_ + o) * T_ + t0 + tt * 32 + hi * 4;
            #pragma unroll
            for (int g = 0; g < 4; ++g) {
                float4 v;
                v.x = a[g * 4 + 0]; v.y = a[g * 4 + 1];
                v.z = a[g * 4 + 2]; v.w = a[g * 4 + 3];
                *(float4*)(yo + g * 8) = v;
            }
        }
}

// ---------------------------------------------------------------------------
// Fallback Phase C (recompute GEMM1) — used only if ws too small.
// ---------------------------------------------------------------------------
__device__ __forceinline__ void gemm1_rc(
    const float* __restrict__ u, const unsigned short* __restrict__ BdKf,
    int b, int k, unsigned short* xs, unsigned short* ut, unsigned short* bb)
{
    const int tid = threadIdx.x;
    const int w = tid >> 6, l = tid & 63, lo = l & 31, hi = l >> 5;
    const int t0 = k * L_;
    f32x16 a00 = zero16(), a01 = zero16(), a10 = zero16(), a11 = zero16();
    for (int kk = 0; kk < 8; ++kk) {
        #pragma unroll
        for (int q = 0; q < 2; ++q) {
            const int i = q * 256 + tid, cl = i >> 4, t4 = i & 15;
            const float4 v = *(const float4*)(
                u + ((size_t)b * C_ + kk * 32 + cl) * T_ + t0 + t4 * 4);
            ut[(t4 * 4 + 0) * 40 + cl] = f2bf(v.x);
            ut[(t4 * 4 + 1) * 40 + cl] = f2bf(v.y);
            ut[(t4 * 4 + 2) * 40 + cl] = f2bf(v.z);
            ut[(t4 * 4 + 3) * 40 + cl] = f2bf(v.w);
        }
        {
            const unsigned short* src = BdKf + kk * 8192;
            #pragma unroll
            for (int q = 0; q < 4; ++q) {
                const int i16 = q * 256 + tid;
                *(int4*)(bb + i16 * 8) = *(const int4*)(src + i16 * 8);
            }
        }
        __syncthreads();
        #pragma unroll
        for (int s = 0; s < 2; ++s) {
            const short8 fa0 = *(const short8*)(ut + (0 * 32 + lo) * 40 + s * 16 + hi * 8);
            const short8 fa1 = *(const short8*)(ut + (1 * 32 + lo) * 40 + s * 16 + hi * 8);
            const short8 fb0 = *(const short8*)(bb + (((2 * w + 0) * 2 + s) * 64 + l) * 8);
            const short8 fb1 = *(const short8*)(bb + (((2 * w + 1) * 2 + s) * 64 + l) * 8);
            a00 = __builtin_amdgcn_mfma_f32_32x32x16_bf16(fa0, fb0, a00, 0, 0, 0);
            a01 = __builtin_amdgcn_mfma_f32_32x32x16_bf16(fa0, fb1, a01, 0, 0, 0);
            a10 = __builtin_amdgcn_mfma_f32_32x32x16_bf16(fa1, fb0, a10, 0, 0, 0);
            a11 = __builtin_amdgcn_mfma_f32_32x32x16_bf16(fa1, fb1, a11, 0, 0, 0);
        }
        __syncthreads();
    }
    #pragma unroll
    for (int tt = 0; tt < 2; ++tt)
        #pragma unroll
        for (int q = 0; q < 2; ++q) {
            const f32x16 a = (tt == 0) ? (q == 0 ? a00 : a01) : (q == 0 ? a10 : a11);
            const int n = (2 * w + q) * 32 + lo;
            #pragma unroll
            for (int g = 0; g < 4; ++g)
                #pragma unroll
                for (int p = 0; p < 2; ++p)
                    *(unsigned*)(xs + n * 66 + tt * 32 + hi * 4 + g * 8 + p * 2)
                        = f2bf(a[g * 4 + 2 * p]) | ((unsigned)f2bf(a[g * 4 + 2 * p + 1]) << 16);
        }
    __syncthreads();
}

__global__ __launch_bounds__(256) void k_phaseC_rc(
    const float* __restrict__ u, const unsigned short* __restrict__ BdKf,
    const unsigned short* __restrict__ CKf, const float* __restrict__ Ad,
    const float* __restrict__ carry, float* __restrict__ y)
{
    __shared__ __align__(16) unsigned short xs[16896];
    __shared__ __align__(16) unsigned short ut[2560];
    __shared__ __align__(16) unsigned short bb[8192];

    const int k = blockIdx.x, b = blockIdx.y;
    const int tid = threadIdx.x;
    const int w = tid >> 6, l = tid & 63, lo = l & 31, hi = l >> 5;
    const int t0 = k * L_;

    gemm1_rc(u, BdKf, b, k, xs, ut, bb);

    {
        const float a = Ad[tid];
        float s = carry[((size_t)k * B_ + b) * N_ + tid];
        float st[64];
        #pragma unroll
        for (int m = 0; m < 32; ++m) {
            const unsigned dw = *(const unsigned*)(xs + tid * 66 + 2 * m);
            s = fmaf(s, a, bf2f((unsigned short)(dw & 0xffff)));  st[2 * m] = s;
            s = fmaf(s, a, bf2f((unsigned short)(dw >> 16)));     st[2 * m + 1] = s;
        }
        __syncthreads();
        #pragma unroll
        for (int t = 0; t < 64; ++t) xs[t * 264 + tid] = f2bf(st[t]);
    }
    __syncthreads();

    f32x16 c00 = zero16(), c01 = zero16(), c10 = zero16(), c11 = zero16();
    for (int kk = 0; kk < 8; ++kk) {
        __syncthreads();
        {
            const unsigned short* src = CKf + kk * 8192;
            #pragma unroll
            for (int q = 0; q < 4; ++q) {
                const int i16 = q * 256 + tid;
                *(int4*)(bb + i16 * 8) = *(const int4*)(src + i16 * 8);
            }
        }
        __syncthreads();
        #pragma unroll
        for (int s = 0; s < 2; ++s) {
            const short8 fa0 = *(const short8*)(xs + (0 * 32 + lo) * 264 + kk * 32 + s * 16 + hi * 8);
            const short8 fa1 = *(const short8*)(xs + (1 * 32 + lo) * 264 + kk * 32 + s * 16 + hi * 8);
            const short8 fb0 = *(const short8*)(bb + (((2 * w + 0) * 2 + s) * 64 + l) * 8);
            const short8 fb1 = *(const short8*)(bb + (((2 * w + 1) * 2 + s) * 64 + l) * 8);
            c00 = __builtin_amdgcn_mfma_f32_32x32x16_bf16(fa0, fb0, c00, 0, 0, 0);
            c01 = __builtin_amdgcn_mfma_f32_32x32x16_bf16(fa0, fb1, c01, 0, 0, 0);
            c10 = __builtin_amdgcn_mfma_f32_32x32x16_bf16(fa1, fb0, c10, 0, 0, 0);
            c11 = __builtin_amdgcn_mfma_f32_32x32x16_bf16(fa1, fb1, c11, 0, 0, 0);
        }
    }

    #pragma unroll
    for (int tt = 0; tt < 2; ++tt)
        #pragma unroll
        for (int q = 0; q < 2; ++q) {
            const f32x16 a = (tt == 0) ? (q == 0 ? c00 : c01) : (q == 0 ? c10 : c11);
            const int o = (2 * w + q) * 32 + lo;
            float* yo = y + ((size_t)b * O_ + o) * T_ + t0 + tt * 32 + hi * 4;
            #pragma unroll
            for (int g = 0; g < 4; ++g) {
                float4 v;
                v.x = a[g * 4 + 0]; v.y = a[g * 4 + 1];
                v.z = a[g * 4 + 2]; v.w = a[g * 4 + 3];
                *(float4*)(yo + g * 8) = v;
            }
        }
}

// ---------------------------------------------------------------------------
extern "C" void kernel_launch(void* const* d_in, const int* in_sizes, int n_in,
                              void* d_out, int out_size, void* d_ws, size_t ws_size,
                              hipStream_t stream)
{
    const float* u  = (const float*)d_in[0];
    const float* rl = (const float*)d_in[1];
    const float* Bc = (const float*)d_in[2];
    const float* Cm = (const float*)d_in[3];
    float* y  = (float*)d_out;
    char*  ws = (char*)d_ws;

    float* Ad     = (float*)(ws + 0);
    float* AL     = (float*)(ws + 1024);
    float* p_last = (float*)(ws + 2048);
    float* carry  = (float*)(ws + 2048 + 2097152);
    unsigned short* BdKf = (unsigned short*)(ws + 2048 + 2 * 2097152);
    unsigned short* CKf  = (unsigned short*)(ws + 2048 + 2 * 2097152 + 131072);
    unsigned short* X    = (unsigned short*)(ws + 2048 + 2 * 2097152 + 2 * 131072);
    const size_t need = 2048 + 2ull * 2097152 + 2ull * 131072
                      + (size_t)NC_ * B_ * 32768;
    const int doX = (ws_size >= need) ? 1 : 0;

    k_prep  <<<dim3(256, 2),  dim3(256), 0, stream>>>(rl, Bc, Cm, Ad, AL, BdKf, CKf);
    k_phaseA<<<dim3(NC_, B_), dim3(256), 0, stream>>>(u, BdKf, Ad, p_last, X, doX);
    k_phaseB<<<dim3(B_),      dim3(256), 0, stream>>>(p_last, AL, carry);
    if (doX)
        k_phaseC<<<dim3(NC_, B_), dim3(256), 0, stream>>>(X, CKf, Ad, carry, y);
    else
        k_phaseC_rc<<<dim3(NC_, B_), dim3(256), 0, stream>>>(u, BdKf, CKf, Ad, carry, y);
}